// Round 1
// baseline (879.465 us; speedup 1.0000x reference)
//
#include <hip/hip_runtime.h>

// TransformerBlock: B=2, S=2048, D=1024, H=16, dh=64, FFN=4096.
// Round 1: correctness-first bf16 MFMA pipeline.

typedef __attribute__((ext_vector_type(8))) short s16x8;
typedef __attribute__((ext_vector_type(4))) float f32x4;
typedef unsigned short u16;

#define DEV static __device__ __forceinline__

DEV u16 f2bf(float f) {
  union { float f; unsigned u; } c; c.f = f;
  unsigned u = c.u;
  u += 0x7fff + ((u >> 16) & 1);   // round-to-nearest-even
  return (u16)(u >> 16);
}

DEV float gelu_tanh(float v) {
  const float c0 = 0.7978845608028654f;  // sqrt(2/pi)
  float u = c0 * (v + 0.044715f * v * v * v);
  return 0.5f * v * (1.0f + tanhf(u));
}

// ---------------- LayerNorm: fp32 [rows,1024] -> bf16 [rows,1024] ----------
__global__ __launch_bounds__(256) void ln_kernel(
    const float* __restrict__ x, const float* __restrict__ g,
    const float* __restrict__ b, u16* __restrict__ out) {
  const int row = blockIdx.x;
  const int t = threadIdx.x;
  const float* xr = x + (size_t)row * 1024;
  float4 v = *(const float4*)(xr + t * 4);
  float s = v.x + v.y + v.z + v.w;
  float ss = v.x * v.x + v.y * v.y + v.z * v.z + v.w * v.w;
#pragma unroll
  for (int off = 1; off < 64; off <<= 1) {
    s += __shfl_xor(s, off);
    ss += __shfl_xor(ss, off);
  }
  __shared__ float sb[4], ssb[4];
  const int w = t >> 6;
  if ((t & 63) == 0) { sb[w] = s; ssb[w] = ss; }
  __syncthreads();
  s = sb[0] + sb[1] + sb[2] + sb[3];
  ss = ssb[0] + ssb[1] + ssb[2] + ssb[3];
  const float mean = s * (1.0f / 1024.0f);
  const float var = ss * (1.0f / 1024.0f) - mean * mean;
  const float rstd = rsqrtf(var + 1e-5f);
  const int c = t * 4;
  ushort4 o;
  o.x = f2bf(g[c + 0] * ((v.x - mean) * rstd) + b[c + 0]);
  o.y = f2bf(g[c + 1] * ((v.y - mean) * rstd) + b[c + 1]);
  o.z = f2bf(g[c + 2] * ((v.z - mean) * rstd) + b[c + 2]);
  o.w = f2bf(g[c + 3] * ((v.w - mean) * rstd) + b[c + 3]);
  *(ushort4*)(out + (size_t)row * 1024 + c) = o;
}

// ---------------- GEMM: C[M,N] = A(bf16)[M,K] @ B(fp32)[K,N] ---------------
// EPI 0: out bf16 scattered to [B*H][S][64] layout (QKV), val *= scale
// EPI 1: out fp32 = val + bias[col] + res[row,col]
// EPI 2: out bf16 = gelu(val + bias[col])
template <int EPI>
__global__ __launch_bounds__(256) void gemm_kernel(
    const u16* __restrict__ A, const float* __restrict__ B,
    const float* __restrict__ bias, const float* __restrict__ res,
    void* __restrict__ Cv, int M, int N, int K, float scale) {
  __shared__ __align__(16) u16 Al[128][32];
  __shared__ __align__(16) u16 Bl[128][32];  // transposed: Bl[n][k]
  const int t = threadIdx.x;
  const int lane = t & 63, w = t >> 6;
  const int wm = (w >> 1) * 64, wn = (w & 1) * 64;
  const int bm = blockIdx.y * 128, bn = blockIdx.x * 128;
  f32x4 acc[4][4] = {};
  const int arow = t >> 2, akc = (t & 3) * 8;
  const int bn8 = (t & 15) * 8, bk = t >> 4;
  const int lr = lane & 15, lk = (lane >> 4) * 8;

  for (int kt = 0; kt < K; kt += 32) {
    __syncthreads();
    // stage A tile 128x32 (bf16, direct)
#pragma unroll
    for (int p = 0; p < 2; ++p) {
      int r = arow + p * 64;
      *(s16x8*)&Al[r][akc] =
          *(const s16x8*)(A + (size_t)(bm + r) * K + kt + akc);
    }
    // stage B tile 32x128 transposed, fp32 -> bf16
#pragma unroll
    for (int p = 0; p < 2; ++p) {
      int k = bk + p * 16;
      const float* bp = B + (size_t)(kt + k) * N + bn + bn8;
      float4 x0 = *(const float4*)bp;
      float4 x1 = *(const float4*)(bp + 4);
      Bl[bn8 + 0][k] = f2bf(x0.x);
      Bl[bn8 + 1][k] = f2bf(x0.y);
      Bl[bn8 + 2][k] = f2bf(x0.z);
      Bl[bn8 + 3][k] = f2bf(x0.w);
      Bl[bn8 + 4][k] = f2bf(x1.x);
      Bl[bn8 + 5][k] = f2bf(x1.y);
      Bl[bn8 + 6][k] = f2bf(x1.z);
      Bl[bn8 + 7][k] = f2bf(x1.w);
    }
    __syncthreads();
    s16x8 af[4], bfr[4];
#pragma unroll
    for (int i = 0; i < 4; ++i) {
      af[i] = *(const s16x8*)&Al[wm + i * 16 + lr][lk];
      bfr[i] = *(const s16x8*)&Bl[wn + i * 16 + lr][lk];
    }
#pragma unroll
    for (int i = 0; i < 4; ++i)
#pragma unroll
      for (int j = 0; j < 4; ++j)
        acc[i][j] = __builtin_amdgcn_mfma_f32_16x16x32_bf16(
            af[i], bfr[j], acc[i][j], 0, 0, 0);
  }

  const int lg = lane >> 4;
#pragma unroll
  for (int i = 0; i < 4; ++i)
#pragma unroll
    for (int j = 0; j < 4; ++j) {
      const int col = bn + wn + j * 16 + lr;
#pragma unroll
      for (int e = 0; e < 4; ++e) {
        const int row = bm + wm + i * 16 + lg * 4 + e;
        float v = acc[i][j][e];
        if (EPI == 0) {
          v *= scale;
          int bb = row >> 11, sloc = row & 2047, hh = col >> 6, dd = col & 63;
          ((u16*)Cv)[((size_t)(bb * 16 + hh) * 2048 + sloc) * 64 + dd] =
              f2bf(v);
        } else if (EPI == 1) {
          v += bias[col] + res[(size_t)row * N + col];
          ((float*)Cv)[(size_t)row * N + col] = v;
        } else {
          v += bias[col];
          ((u16*)Cv)[(size_t)row * N + col] = f2bf(gelu_tanh(v));
        }
      }
    }
}

// ---------------- Flash attention (causal), bf16 MFMA ----------------------
// Q,K,V: [B*H][S=2048][64] bf16 (q pre-scaled by 1/8). ctx out: [B*S][1024] bf16.
__global__ __launch_bounds__(256) void attn_kernel(
    const u16* __restrict__ Qg, const u16* __restrict__ Kg,
    const u16* __restrict__ Vg, u16* __restrict__ ctx) {
  __shared__ __align__(16) u16 Ql[64][64];
  __shared__ __align__(16) u16 Kl[32][64];
  __shared__ __align__(16) u16 Vt[64][32];      // transposed: Vt[d][key]
  __shared__ __align__(16) u16 Pl[4][16][32];   // per-wave P tile
  const int t = threadIdx.x, lane = t & 63, w = t >> 6;
  const int qb = blockIdx.x, bh = blockIdx.y;
  const size_t base = (size_t)bh * 2048 * 64;
  const int lr = lane & 15, lg = lane >> 4;

  // stage Q block 64x64
#pragma unroll
  for (int p = 0; p < 2; ++p) {
    int e = p * 2048 + t * 8;
    int r = e >> 6, c = e & 63;
    *(s16x8*)&Ql[r][c] =
        *(const s16x8*)(Qg + base + (size_t)(qb * 64 + r) * 64 + c);
  }
  __syncthreads();
  const s16x8 aq0 = *(const s16x8*)&Ql[w * 16 + lr][lg * 8];
  const s16x8 aq1 = *(const s16x8*)&Ql[w * 16 + lr][32 + lg * 8];

  float m_run[4], l_run[4];
  f32x4 acco[4] = {};
#pragma unroll
  for (int j = 0; j < 4; ++j) { m_run[j] = -INFINITY; l_run[j] = 0.0f; }

  const int nt = qb * 2 + 2;  // causal: keys <= qb*64+63
  for (int kt = 0; kt < nt; ++kt) {
    const int k0 = kt * 32;
    __syncthreads();
    {  // stage K tile 32x64
      int e = t * 8;
      int r = e >> 6, c = e & 63;
      *(s16x8*)&Kl[r][c] =
          *(const s16x8*)(Kg + base + (size_t)(k0 + r) * 64 + c);
    }
    {  // stage V tile transposed -> Vt[d][key]
      int key = t >> 3, d0 = (t & 7) * 8;
      s16x8 v8 = *(const s16x8*)(Vg + base + (size_t)(k0 + key) * 64 + d0);
#pragma unroll
      for (int i = 0; i < 8; ++i) Vt[d0 + i][key] = (u16)v8[i];
    }
    __syncthreads();

    // S = Q @ K^T  (16 q-rows x 32 keys per wave)
    f32x4 sc0 = {}, sc1 = {};
    {
      s16x8 b00 = *(const s16x8*)&Kl[lr][lg * 8];
      s16x8 b01 = *(const s16x8*)&Kl[lr][32 + lg * 8];
      s16x8 b10 = *(const s16x8*)&Kl[16 + lr][lg * 8];
      s16x8 b11 = *(const s16x8*)&Kl[16 + lr][32 + lg * 8];
      sc0 = __builtin_amdgcn_mfma_f32_16x16x32_bf16(aq0, b00, sc0, 0, 0, 0);
      sc0 = __builtin_amdgcn_mfma_f32_16x16x32_bf16(aq1, b01, sc0, 0, 0, 0);
      sc1 = __builtin_amdgcn_mfma_f32_16x16x32_bf16(aq0, b10, sc1, 0, 0, 0);
      sc1 = __builtin_amdgcn_mfma_f32_16x16x32_bf16(aq1, b11, sc1, 0, 0, 0);
    }

    // online softmax per q-row (row = lg*4 + j, key col = lr)
    const int qrb = qb * 64 + w * 16 + lg * 4;
    float scl[4];
#pragma unroll
    for (int j = 0; j < 4; ++j) {
      float s0 = sc0[j], s1 = sc1[j];
      const int qi = qrb + j;
      if (k0 + lr > qi) s0 = -INFINITY;
      if (k0 + 16 + lr > qi) s1 = -INFINITY;
      float mt = fmaxf(s0, s1);
#pragma unroll
      for (int off = 1; off < 16; off <<= 1) mt = fmaxf(mt, __shfl_xor(mt, off));
      const float mn = fmaxf(m_run[j], mt);
      const float sf = expf(m_run[j] - mn);
      const float p0 = expf(s0 - mn), p1 = expf(s1 - mn);
      float rs = p0 + p1;
#pragma unroll
      for (int off = 1; off < 16; off <<= 1) rs += __shfl_xor(rs, off);
      l_run[j] = l_run[j] * sf + rs;
      m_run[j] = mn;
      scl[j] = sf;
      Pl[w][lg * 4 + j][lr] = f2bf(p0);
      Pl[w][lg * 4 + j][16 + lr] = f2bf(p1);
    }
#pragma unroll
    for (int c = 0; c < 4; ++c) {
      f32x4 a = acco[c];
      a[0] *= scl[0]; a[1] *= scl[1]; a[2] *= scl[2]; a[3] *= scl[3];
      acco[c] = a;
    }
    __syncthreads();  // P visible to all lanes of the wave

    // O += P @ V
    const s16x8 pa = *(const s16x8*)&Pl[w][lr][lg * 8];
#pragma unroll
    for (int c = 0; c < 4; ++c) {
      s16x8 bv = *(const s16x8*)&Vt[c * 16 + lr][lg * 8];
      acco[c] = __builtin_amdgcn_mfma_f32_16x16x32_bf16(pa, bv, acco[c], 0, 0, 0);
    }
  }

  // epilogue: ctx[b*2048+s][h*64+d] bf16
  const int bb = bh >> 4, hh = bh & 15;
#pragma unroll
  for (int c = 0; c < 4; ++c)
#pragma unroll
    for (int e = 0; e < 4; ++e) {
      const int qs = qb * 64 + w * 16 + lg * 4 + e;
      const int d = c * 16 + lr;
      const float v = acco[c][e] / l_run[e];
      ctx[(size_t)(bb * 2048 + qs) * 1024 + hh * 64 + d] = f2bf(v);
    }
}

// ---------------------------------------------------------------------------
extern "C" void kernel_launch(void* const* d_in, const int* in_sizes, int n_in,
                              void* d_out, int out_size, void* d_ws,
                              size_t ws_size, hipStream_t stream) {
  const float* x  = (const float*)d_in[0];
  const float* wq = (const float*)d_in[1];
  const float* wk = (const float*)d_in[2];
  const float* wv = (const float*)d_in[3];
  const float* wo = (const float*)d_in[4];
  const float* bo = (const float*)d_in[5];
  const float* w1 = (const float*)d_in[6];
  const float* b1 = (const float*)d_in[7];
  const float* w2 = (const float*)d_in[8];
  const float* b2 = (const float*)d_in[9];
  const float* g1 = (const float*)d_in[10];
  const float* s1 = (const float*)d_in[11];
  const float* g2 = (const float*)d_in[12];
  const float* s2 = (const float*)d_in[13];
  float* out = (float*)d_out;

  // workspace layout (96 MB total)
  char* p = (char*)d_ws;
  u16* hb   = (u16*)p;  p += (size_t)8 << 20;   // LN1 out bf16 [4096,1024]
  u16* qb   = (u16*)p;  p += (size_t)8 << 20;   // [32][2048][64]
  u16* kb   = (u16*)p;  p += (size_t)8 << 20;
  u16* vb   = (u16*)p;  p += (size_t)8 << 20;
  u16* ctxb = (u16*)p;  p += (size_t)8 << 20;   // [4096,1024] bf16
  float* x2 = (float*)p; p += (size_t)16 << 20; // residual fp32 [4096,1024]
  u16* h2b  = (u16*)p;  p += (size_t)8 << 20;   // LN2 out bf16
  u16* gb   = (u16*)p;  p += (size_t)32 << 20;  // gelu out bf16 [4096,4096]

  const dim3 blk(256);
  const dim3 gD(1024 / 128, 4096 / 128);   // N=1024 GEMMs
  const dim3 gF(4096 / 128, 4096 / 128);   // FFN1

  ln_kernel<<<4096, blk, 0, stream>>>(x, g1, s1, hb);
  gemm_kernel<0><<<gD, blk, 0, stream>>>(hb, wq, nullptr, nullptr, qb, 4096, 1024, 1024, 0.125f);
  gemm_kernel<0><<<gD, blk, 0, stream>>>(hb, wk, nullptr, nullptr, kb, 4096, 1024, 1024, 1.0f);
  gemm_kernel<0><<<gD, blk, 0, stream>>>(hb, wv, nullptr, nullptr, vb, 4096, 1024, 1024, 1.0f);
  attn_kernel<<<dim3(32, 32), blk, 0, stream>>>(qb, kb, vb, ctxb);
  gemm_kernel<1><<<gD, blk, 0, stream>>>(ctxb, wo, bo, x, x2, 4096, 1024, 1024, 1.0f);
  ln_kernel<<<4096, blk, 0, stream>>>(x2, g2, s2, h2b);
  gemm_kernel<2><<<gF, blk, 0, stream>>>(h2b, w1, b1, nullptr, gb, 4096, 4096, 1024, 1.0f);
  gemm_kernel<1><<<gD, blk, 0, stream>>>(gb, w2, b2, x2, out, 4096, 1024, 4096, 1.0f);
}

// Round 2
// 491.843 us; speedup vs baseline: 1.7881x; 1.7881x over previous
//
#include <hip/hip_runtime.h>

// TransformerBlock: B=2, S=2048, D=1024, H=16, dh=64, FFN=4096.
// Round 2: barrier-free flash attention (V pre-transposed), bf16 weight
// pre-transpose, m97-style global_load_lds GEMM.

typedef __attribute__((ext_vector_type(8))) short s16x8;
typedef __attribute__((ext_vector_type(4))) float f32x4;
typedef unsigned short u16;

#define DEV static __device__ __forceinline__
#define MFMA16 __builtin_amdgcn_mfma_f32_16x16x32_bf16
#define GLOAD_LDS16(gp, lp)                                         \
  __builtin_amdgcn_global_load_lds(                                 \
      (const __attribute__((address_space(1))) void*)(gp),          \
      (__attribute__((address_space(3))) void*)(lp), 16, 0, 0)

DEV u16 f2bf(float f) {
  union { float f; unsigned u; } c; c.f = f;
  unsigned u = c.u;
  u += 0x7fff + ((u >> 16) & 1);   // RNE
  return (u16)(u >> 16);
}

DEV float gelu_tanh(float v) {
  const float c0 = 0.7978845608028654f;  // sqrt(2/pi)
  float u = c0 * (v + 0.044715f * v * v * v);
  return 0.5f * v * (1.0f + tanhf(u));
}

// ---------- transpose + convert: W fp32 [K,N] -> Wt bf16 [N,K] -------------
__global__ __launch_bounds__(256) void tconv_kernel(
    const float* __restrict__ W, u16* __restrict__ Wt, int K, int N) {
  __shared__ u16 T[64][80];
  const int t = threadIdx.x;
  const int n0 = blockIdx.x * 64, k0 = blockIdx.y * 64;
  const int kr = t >> 4, nc = (t & 15) * 4;
#pragma unroll
  for (int p = 0; p < 4; ++p) {
    const int k = p * 16 + kr;
    float4 v = *(const float4*)(W + (size_t)(k0 + k) * N + n0 + nc);
    T[nc + 0][k] = f2bf(v.x);
    T[nc + 1][k] = f2bf(v.y);
    T[nc + 2][k] = f2bf(v.z);
    T[nc + 3][k] = f2bf(v.w);
  }
  __syncthreads();
  const int nr = t >> 2, kc = (t & 3) * 16;
  *(s16x8*)(Wt + (size_t)(n0 + nr) * K + k0 + kc) = *(const s16x8*)&T[nr][kc];
  *(s16x8*)(Wt + (size_t)(n0 + nr) * K + k0 + kc + 8) =
      *(const s16x8*)&T[nr][kc + 8];
}

// ---------------- LayerNorm: fp32 [rows,1024] -> bf16 [rows,1024] ----------
__global__ __launch_bounds__(256) void ln_kernel(
    const float* __restrict__ x, const float* __restrict__ g,
    const float* __restrict__ b, u16* __restrict__ out) {
  const int row = blockIdx.x;
  const int t = threadIdx.x;
  const float* xr = x + (size_t)row * 1024;
  float4 v = *(const float4*)(xr + t * 4);
  float s = v.x + v.y + v.z + v.w;
  float ss = v.x * v.x + v.y * v.y + v.z * v.z + v.w * v.w;
#pragma unroll
  for (int off = 1; off < 64; off <<= 1) {
    s += __shfl_xor(s, off);
    ss += __shfl_xor(ss, off);
  }
  __shared__ float sb[4], ssb[4];
  const int w = t >> 6;
  if ((t & 63) == 0) { sb[w] = s; ssb[w] = ss; }
  __syncthreads();
  s = sb[0] + sb[1] + sb[2] + sb[3];
  ss = ssb[0] + ssb[1] + ssb[2] + ssb[3];
  const float mean = s * (1.0f / 1024.0f);
  const float var = ss * (1.0f / 1024.0f) - mean * mean;
  const float rstd = rsqrtf(var + 1e-5f);
  const int c = t * 4;
  ushort4 o;
  o.x = f2bf(g[c + 0] * ((v.x - mean) * rstd) + b[c + 0]);
  o.y = f2bf(g[c + 1] * ((v.y - mean) * rstd) + b[c + 1]);
  o.z = f2bf(g[c + 2] * ((v.z - mean) * rstd) + b[c + 2]);
  o.w = f2bf(g[c + 3] * ((v.w - mean) * rstd) + b[c + 3]);
  *(ushort4*)(out + (size_t)row * 1024 + c) = o;
}

// ---------------- GEMM: C[M,N] = A(bf16)[M,K] @ Bt(bf16)[N,K]^T ------------
// EPI 0: QKV fused (N=3072): q/k -> [bh][s][64] bf16 (q*0.125), v -> [bh][64][s]
// EPI 1: out fp32 = val + bias[col] + res[row,col]
// EPI 2: out bf16 = gelu(val + bias[col])
template <int EPI>
__global__ __launch_bounds__(256) void gemm_kernel(
    const u16* __restrict__ A, const u16* __restrict__ Bt,
    const float* __restrict__ bias, const float* __restrict__ res,
    void* __restrict__ Cv, int M, int N, int K) {
  __shared__ __align__(16) u16 Al[128][32];
  __shared__ __align__(16) u16 Bl[128][32];
  const int t = threadIdx.x;
  const int lane = t & 63, w = t >> 6;
  const int wm = (w >> 1) * 64, wn = (w & 1) * 64;
  const int bm = blockIdx.y * 128, bn = blockIdx.x * 128;
  const int lr = lane & 15, lg = lane >> 4;
  const int srow = lane >> 2, scol = (lane & 3) * 8;  // staging map (16B/lane)
  f32x4 acc[4][4] = {};

  for (int kt = 0; kt < K; kt += 32) {
    __syncthreads();
#pragma unroll
    for (int p = 0; p < 2; ++p) {
      const int r0 = (w * 2 + p) * 16;
      GLOAD_LDS16(A + (size_t)(bm + r0 + srow) * K + kt + scol, &Al[r0][0]);
      GLOAD_LDS16(Bt + (size_t)(bn + r0 + srow) * K + kt + scol, &Bl[r0][0]);
    }
    __syncthreads();
    s16x8 af[4], bf[4];
#pragma unroll
    for (int i = 0; i < 4; ++i) {
      af[i] = *(const s16x8*)&Al[wm + i * 16 + lr][lg * 8];
      bf[i] = *(const s16x8*)&Bl[wn + i * 16 + lr][lg * 8];
    }
#pragma unroll
    for (int i = 0; i < 4; ++i)
#pragma unroll
      for (int j = 0; j < 4; ++j)
        acc[i][j] = MFMA16(af[i], bf[j], acc[i][j], 0, 0, 0);
  }

#pragma unroll
  for (int i = 0; i < 4; ++i) {
    const int row = bm + wm + i * 16 + lg * 4;  // + e
#pragma unroll
    for (int j = 0; j < 4; ++j) {
      const int col = bn + wn + j * 16 + lr;
      if (EPI == 0) {
        const int bb = row >> 11, sloc = row & 2047;
        const int which = col >> 10, n = col & 1023;
        const int hh = n >> 6, dd = n & 63;
        u16* qbuf = (u16*)Cv;
        if (which == 2) {  // V transposed [bh][64][2048]
          ushort4 o;
          o.x = f2bf(acc[i][j][0]); o.y = f2bf(acc[i][j][1]);
          o.z = f2bf(acc[i][j][2]); o.w = f2bf(acc[i][j][3]);
          *(ushort4*)(qbuf + 8388608 +
                      (size_t)((bb * 16 + hh) * 64 + dd) * 2048 + sloc) = o;
        } else {
          const float sc = (which == 0) ? 0.125f : 1.0f;
          u16* dst = qbuf + (size_t)which * 4194304 +
                     ((size_t)(bb * 16 + hh) * 2048 + sloc) * 64 + dd;
#pragma unroll
          for (int e = 0; e < 4; ++e) dst[(size_t)e * 64] = f2bf(acc[i][j][e] * sc);
        }
      } else if (EPI == 1) {
        float* C = (float*)Cv;
        const float bs = bias[col];
#pragma unroll
        for (int e = 0; e < 4; ++e)
          C[(size_t)(row + e) * N + col] =
              acc[i][j][e] + bs + res[(size_t)(row + e) * N + col];
      } else {
        u16* C = (u16*)Cv;
        const float bs = bias[col];
#pragma unroll
        for (int e = 0; e < 4; ++e)
          C[(size_t)(row + e) * N + col] = f2bf(gelu_tanh(acc[i][j][e] + bs));
      }
    }
  }
}

// ---------------- Flash attention (causal), barrier-free, 1 wave/block -----
// Qg,Kg: [32][2048][64] bf16 (q pre-scaled); Vt: [32][64][2048] bf16.
// Block = 64 threads = 1 wave, owns 16 q-rows. Grid (128, 32).
__global__ __launch_bounds__(64) void attn_kernel(
    const u16* __restrict__ Qg, const u16* __restrict__ Kg,
    const u16* __restrict__ Vt, u16* __restrict__ ctx) {
  __shared__ __align__(16) u16 Pl[16][64];  // XOR-swizzled cols
  const int lane = threadIdx.x & 63;
  const int wx = blockIdx.x, bh = blockIdx.y;
  const int lr = lane & 15, lg = lane >> 4;
  const int qs = wx * 16;
  const size_t baseK = (size_t)bh * 2048 * 64;
  const size_t baseV = (size_t)bh * 64 * 2048;

  const u16* qp = Qg + baseK + (size_t)(qs + lr) * 64 + lg * 8;
  const s16x8 aq0 = *(const s16x8*)qp;
  const s16x8 aq1 = *(const s16x8*)(qp + 32);

  float m_run[4], l_run[4];
  f32x4 acco[4] = {};
#pragma unroll
  for (int e = 0; e < 4; ++e) { m_run[e] = -INFINITY; l_run[e] = 0.f; }

  const int ntiles = (qs >> 6) + 1;
  for (int kt = 0; kt < ntiles; ++kt) {
    const int k0 = kt * 64;
    // ---- S = Q K^T : 16 q x 64 keys ----
    f32x4 sc[4];
#pragma unroll
    for (int s = 0; s < 4; ++s) {
      const u16* kp = Kg + baseK + (size_t)(k0 + s * 16 + lr) * 64 + lg * 8;
      s16x8 b0 = *(const s16x8*)kp;
      s16x8 b1 = *(const s16x8*)(kp + 32);
      f32x4 a = {};
      a = MFMA16(aq0, b0, a, 0, 0, 0);
      a = MFMA16(aq1, b1, a, 0, 0, 0);
      sc[s] = a;
    }
    if (k0 + 63 > qs) {  // diagonal tile: causal mask
#pragma unroll
      for (int s = 0; s < 4; ++s)
#pragma unroll
        for (int e = 0; e < 4; ++e)
          if (k0 + s * 16 + lr > qs + lg * 4 + e) sc[s][e] = -INFINITY;
    }
    // ---- online softmax (row = lg*4+e, key cols = s*16+lr) ----
    float scl[4];
#pragma unroll
    for (int e = 0; e < 4; ++e) {
      float mt = fmaxf(fmaxf(sc[0][e], sc[1][e]), fmaxf(sc[2][e], sc[3][e]));
#pragma unroll
      for (int o = 1; o < 16; o <<= 1) mt = fmaxf(mt, __shfl_xor(mt, o));
      const float mn = fmaxf(m_run[e], mt);
      const float sf = __expf(m_run[e] - mn);
      float p0 = __expf(sc[0][e] - mn), p1 = __expf(sc[1][e] - mn);
      float p2 = __expf(sc[2][e] - mn), p3 = __expf(sc[3][e] - mn);
      float rs = p0 + p1 + p2 + p3;
#pragma unroll
      for (int o = 1; o < 16; o <<= 1) rs += __shfl_xor(rs, o);
      l_run[e] = l_run[e] * sf + rs;
      m_run[e] = mn;
      scl[e] = sf;
      const int r = lg * 4 + e, sw = lg << 4;  // swizzle: col ^= (r>>2)<<4
      Pl[r][(0 * 16 + lr) ^ sw] = f2bf(p0);
      Pl[r][(1 * 16 + lr) ^ sw] = f2bf(p1);
      Pl[r][(2 * 16 + lr) ^ sw] = f2bf(p2);
      Pl[r][(3 * 16 + lr) ^ sw] = f2bf(p3);
    }
#pragma unroll
    for (int c = 0; c < 4; ++c) {
      acco[c][0] *= scl[0]; acco[c][1] *= scl[1];
      acco[c][2] *= scl[2]; acco[c][3] *= scl[3];
    }
    // ---- O += P V ----
    const int rsw = (lr >> 2) << 4;
    const s16x8 pa0 = *(const s16x8*)&Pl[lr][(lg * 8) ^ rsw];
    const s16x8 pa1 = *(const s16x8*)&Pl[lr][(32 + lg * 8) ^ rsw];
#pragma unroll
    for (int c = 0; c < 4; ++c) {
      const u16* vp = Vt + baseV + (size_t)(c * 16 + lr) * 2048 + k0 + lg * 8;
      s16x8 v0 = *(const s16x8*)vp;
      s16x8 v1 = *(const s16x8*)(vp + 32);
      acco[c] = MFMA16(pa0, v0, acco[c], 0, 0, 0);
      acco[c] = MFMA16(pa1, v1, acco[c], 0, 0, 0);
    }
  }
  // epilogue: ctx[b*2048+q][h*64+d] bf16
  const int bb = bh >> 4, hh = bh & 15;
#pragma unroll
  for (int c = 0; c < 4; ++c) {
    const int d = c * 16 + lr;
#pragma unroll
    for (int e = 0; e < 4; ++e) {
      const int q = qs + lg * 4 + e;
      ctx[(size_t)(bb * 2048 + q) * 1024 + hh * 64 + d] =
          f2bf(acco[c][e] / l_run[e]);
    }
  }
}

// ---------------------------------------------------------------------------
extern "C" void kernel_launch(void* const* d_in, const int* in_sizes, int n_in,
                              void* d_out, int out_size, void* d_ws,
                              size_t ws_size, hipStream_t stream) {
  const float* x  = (const float*)d_in[0];
  const float* wq = (const float*)d_in[1];
  const float* wk = (const float*)d_in[2];
  const float* wv = (const float*)d_in[3];
  const float* wo = (const float*)d_in[4];
  const float* bo = (const float*)d_in[5];
  const float* w1 = (const float*)d_in[6];
  const float* b1 = (const float*)d_in[7];
  const float* w2 = (const float*)d_in[8];
  const float* b2 = (const float*)d_in[9];
  const float* g1 = (const float*)d_in[10];
  const float* s1 = (const float*)d_in[11];
  const float* g2 = (const float*)d_in[12];
  const float* s2 = (const float*)d_in[13];
  float* out = (float*)d_out;

  const size_t MB = (size_t)1 << 20;
  char* p = (char*)d_ws;
  u16* hb    = (u16*)(p + 0 * MB);    // LN1 out bf16 [4096,1024]       (8MB)
  u16* qbuf  = (u16*)(p + 8 * MB);    // q[32][2048][64] | k same | vt[32][64][2048]  (24MB)
  u16* ctxb  = (u16*)(p + 32 * MB);   // [4096,1024] bf16               (8MB)
  float* x2  = (float*)(p + 40 * MB); // residual fp32 [4096,1024]      (16MB)
  u16* h2b   = (u16*)(p + 56 * MB);   // LN2 out bf16                   (8MB)
  u16* qkvw  = (u16*)(p + 64 * MB);   // [3072][1024] bf16 packed Wq/Wk/Wv^T (6MB)
  u16* wot   = (u16*)(p + 70 * MB);   // [1024][1024]                   (2MB)
  u16* w1t   = (u16*)(p + 72 * MB);   // [4096][1024]                   (8MB)
  u16* w2t   = (u16*)(p + 80 * MB);   // [1024][4096]                   (8MB)
  u16* gb    = (u16*)(p + 0 * MB);    // gelu out bf16 [4096,4096], aliases hb/qbuf (32MB)

  const dim3 blk(256);
  // weight prep
  tconv_kernel<<<dim3(16, 16), blk, 0, stream>>>(wq, qkvw, 1024, 1024);
  tconv_kernel<<<dim3(16, 16), blk, 0, stream>>>(wk, qkvw + 1048576, 1024, 1024);
  tconv_kernel<<<dim3(16, 16), blk, 0, stream>>>(wv, qkvw + 2097152, 1024, 1024);
  tconv_kernel<<<dim3(16, 16), blk, 0, stream>>>(wo, wot, 1024, 1024);
  tconv_kernel<<<dim3(64, 16), blk, 0, stream>>>(w1, w1t, 1024, 4096);
  tconv_kernel<<<dim3(16, 64), blk, 0, stream>>>(w2, w2t, 4096, 1024);

  ln_kernel<<<4096, blk, 0, stream>>>(x, g1, s1, hb);
  gemm_kernel<0><<<dim3(24, 32), blk, 0, stream>>>(hb, qkvw, nullptr, nullptr,
                                                   qbuf, 4096, 3072, 1024);
  attn_kernel<<<dim3(128, 32), dim3(64), 0, stream>>>(
      qbuf, qbuf + 4194304, qbuf + 8388608, ctxb);
  gemm_kernel<1><<<dim3(8, 32), blk, 0, stream>>>(ctxb, wot, bo, x, x2, 4096,
                                                  1024, 1024);
  ln_kernel<<<4096, blk, 0, stream>>>(x2, g2, s2, h2b);
  gemm_kernel<2><<<dim3(32, 32), blk, 0, stream>>>(h2b, w1t, b1, nullptr, gb,
                                                   4096, 4096, 1024);
  gemm_kernel<1><<<dim3(8, 32), blk, 0, stream>>>(gb, w2t, b2, x2, out, 4096,
                                                  1024, 4096);
}

// Round 3
// 387.698 us; speedup vs baseline: 2.2684x; 1.2686x over previous
//
#include <hip/hip_runtime.h>

// TransformerBlock: B=2, S=2048, D=1024, H=16, dh=64, FFN=4096.
// Round 3: paired-causal dual-chain flash attention (ILP + load balance).

typedef __attribute__((ext_vector_type(8))) short s16x8;
typedef __attribute__((ext_vector_type(4))) float f32x4;
typedef unsigned short u16;

#define DEV static __device__ __forceinline__
#define MFMA16 __builtin_amdgcn_mfma_f32_16x16x32_bf16
#define GLOAD_LDS16(gp, lp)                                         \
  __builtin_amdgcn_global_load_lds(                                 \
      (const __attribute__((address_space(1))) void*)(gp),          \
      (__attribute__((address_space(3))) void*)(lp), 16, 0, 0)

DEV u16 f2bf(float f) {
  union { float f; unsigned u; } c; c.f = f;
  unsigned u = c.u;
  u += 0x7fff + ((u >> 16) & 1);   // RNE
  return (u16)(u >> 16);
}

DEV float gelu_tanh(float v) {
  const float c0 = 0.7978845608028654f;  // sqrt(2/pi)
  float u = c0 * (v + 0.044715f * v * v * v);
  return 0.5f * v * (1.0f + tanhf(u));
}

// ---------- transpose + convert: W fp32 [K,N] -> Wt bf16 [N,K] -------------
__global__ __launch_bounds__(256) void tconv_kernel(
    const float* __restrict__ W, u16* __restrict__ Wt, int K, int N) {
  __shared__ u16 T[64][80];
  const int t = threadIdx.x;
  const int n0 = blockIdx.x * 64, k0 = blockIdx.y * 64;
  const int kr = t >> 4, nc = (t & 15) * 4;
#pragma unroll
  for (int p = 0; p < 4; ++p) {
    const int k = p * 16 + kr;
    float4 v = *(const float4*)(W + (size_t)(k0 + k) * N + n0 + nc);
    T[nc + 0][k] = f2bf(v.x);
    T[nc + 1][k] = f2bf(v.y);
    T[nc + 2][k] = f2bf(v.z);
    T[nc + 3][k] = f2bf(v.w);
  }
  __syncthreads();
  const int nr = t >> 2, kc = (t & 3) * 16;
  *(s16x8*)(Wt + (size_t)(n0 + nr) * K + k0 + kc) = *(const s16x8*)&T[nr][kc];
  *(s16x8*)(Wt + (size_t)(n0 + nr) * K + k0 + kc + 8) =
      *(const s16x8*)&T[nr][kc + 8];
}

// ---------------- LayerNorm: fp32 [rows,1024] -> bf16 [rows,1024] ----------
__global__ __launch_bounds__(256) void ln_kernel(
    const float* __restrict__ x, const float* __restrict__ g,
    const float* __restrict__ b, u16* __restrict__ out) {
  const int row = blockIdx.x;
  const int t = threadIdx.x;
  const float* xr = x + (size_t)row * 1024;
  float4 v = *(const float4*)(xr + t * 4);
  float s = v.x + v.y + v.z + v.w;
  float ss = v.x * v.x + v.y * v.y + v.z * v.z + v.w * v.w;
#pragma unroll
  for (int off = 1; off < 64; off <<= 1) {
    s += __shfl_xor(s, off);
    ss += __shfl_xor(ss, off);
  }
  __shared__ float sb[4], ssb[4];
  const int w = t >> 6;
  if ((t & 63) == 0) { sb[w] = s; ssb[w] = ss; }
  __syncthreads();
  s = sb[0] + sb[1] + sb[2] + sb[3];
  ss = ssb[0] + ssb[1] + ssb[2] + ssb[3];
  const float mean = s * (1.0f / 1024.0f);
  const float var = ss * (1.0f / 1024.0f) - mean * mean;
  const float rstd = rsqrtf(var + 1e-5f);
  const int c = t * 4;
  ushort4 o;
  o.x = f2bf(g[c + 0] * ((v.x - mean) * rstd) + b[c + 0]);
  o.y = f2bf(g[c + 1] * ((v.y - mean) * rstd) + b[c + 1]);
  o.z = f2bf(g[c + 2] * ((v.z - mean) * rstd) + b[c + 2]);
  o.w = f2bf(g[c + 3] * ((v.w - mean) * rstd) + b[c + 3]);
  *(ushort4*)(out + (size_t)row * 1024 + c) = o;
}

// ---------------- GEMM: C[M,N] = A(bf16)[M,K] @ Bt(bf16)[N,K]^T ------------
template <int EPI>
__global__ __launch_bounds__(256) void gemm_kernel(
    const u16* __restrict__ A, const u16* __restrict__ Bt,
    const float* __restrict__ bias, const float* __restrict__ res,
    void* __restrict__ Cv, int M, int N, int K) {
  __shared__ __align__(16) u16 Al[128][32];
  __shared__ __align__(16) u16 Bl[128][32];
  const int t = threadIdx.x;
  const int lane = t & 63, w = t >> 6;
  const int wm = (w >> 1) * 64, wn = (w & 1) * 64;
  const int bm = blockIdx.y * 128, bn = blockIdx.x * 128;
  const int lr = lane & 15, lg = lane >> 4;
  const int srow = lane >> 2, scol = (lane & 3) * 8;
  f32x4 acc[4][4] = {};

  for (int kt = 0; kt < K; kt += 32) {
    __syncthreads();
#pragma unroll
    for (int p = 0; p < 2; ++p) {
      const int r0 = (w * 2 + p) * 16;
      GLOAD_LDS16(A + (size_t)(bm + r0 + srow) * K + kt + scol, &Al[r0][0]);
      GLOAD_LDS16(Bt + (size_t)(bn + r0 + srow) * K + kt + scol, &Bl[r0][0]);
    }
    __syncthreads();
    s16x8 af[4], bf[4];
#pragma unroll
    for (int i = 0; i < 4; ++i) {
      af[i] = *(const s16x8*)&Al[wm + i * 16 + lr][lg * 8];
      bf[i] = *(const s16x8*)&Bl[wn + i * 16 + lr][lg * 8];
    }
#pragma unroll
    for (int i = 0; i < 4; ++i)
#pragma unroll
      for (int j = 0; j < 4; ++j)
        acc[i][j] = MFMA16(af[i], bf[j], acc[i][j], 0, 0, 0);
  }

#pragma unroll
  for (int i = 0; i < 4; ++i) {
    const int row = bm + wm + i * 16 + lg * 4;  // + e
#pragma unroll
    for (int j = 0; j < 4; ++j) {
      const int col = bn + wn + j * 16 + lr;
      if (EPI == 0) {
        const int bb = row >> 11, sloc = row & 2047;
        const int which = col >> 10, n = col & 1023;
        const int hh = n >> 6, dd = n & 63;
        u16* qbuf = (u16*)Cv;
        if (which == 2) {  // V transposed [bh][64][2048]
          ushort4 o;
          o.x = f2bf(acc[i][j][0]); o.y = f2bf(acc[i][j][1]);
          o.z = f2bf(acc[i][j][2]); o.w = f2bf(acc[i][j][3]);
          *(ushort4*)(qbuf + 8388608 +
                      (size_t)((bb * 16 + hh) * 64 + dd) * 2048 + sloc) = o;
        } else {
          const float sc = (which == 0) ? 0.125f : 1.0f;
          u16* dst = qbuf + (size_t)which * 4194304 +
                     ((size_t)(bb * 16 + hh) * 2048 + sloc) * 64 + dd;
#pragma unroll
          for (int e = 0; e < 4; ++e) dst[(size_t)e * 64] = f2bf(acc[i][j][e] * sc);
        }
      } else if (EPI == 1) {
        float* C = (float*)Cv;
        const float bs = bias[col];
#pragma unroll
        for (int e = 0; e < 4; ++e)
          C[(size_t)(row + e) * N + col] =
              acc[i][j][e] + bs + res[(size_t)(row + e) * N + col];
      } else {
        u16* C = (u16*)Cv;
        const float bs = bias[col];
#pragma unroll
        for (int e = 0; e < 4; ++e)
          C[(size_t)(row + e) * N + col] = f2bf(gelu_tanh(acc[i][j][e] + bs));
      }
    }
  }
}

// ---------------- Flash attention: paired-causal dual-chain ----------------
// Qg,Kg: [32][2048][64] bf16 (q pre-scaled); Vt: [32][64][2048] bf16.
// Block = 1 wave. wx in [0,64): chain A = q-tile wx, chain B = q-tile 127-wx.
struct AttnChain {
  s16x8 aq0, aq1;
  f32x4 acco[4];
  float m[4], l[4];
};

template <bool DIAG>
DEV void attn_tile(AttnChain& st, int k0, int qs, const u16* Kbase,
                   const u16* Vbase, u16 (*Pl)[64], int lr, int lg) {
  // K fragments
  s16x8 kb[4][2];
#pragma unroll
  for (int s = 0; s < 4; ++s) {
    const u16* kp = Kbase + (size_t)(k0 + s * 16 + lr) * 64 + lg * 8;
    kb[s][0] = *(const s16x8*)kp;
    kb[s][1] = *(const s16x8*)(kp + 32);
  }
  f32x4 sc[4];
#pragma unroll
  for (int s = 0; s < 4; ++s) {
    f32x4 a = {};
    a = MFMA16(st.aq0, kb[s][0], a, 0, 0, 0);
    a = MFMA16(st.aq1, kb[s][1], a, 0, 0, 0);
    sc[s] = a;
  }
  // V fragments — issue before softmax so they're in flight during shfls
  s16x8 vb[4][2];
#pragma unroll
  for (int c = 0; c < 4; ++c) {
    const u16* vp = Vbase + (size_t)(c * 16 + lr) * 2048 + k0 + lg * 8;
    vb[c][0] = *(const s16x8*)vp;
    vb[c][1] = *(const s16x8*)(vp + 32);
  }
  if (DIAG) {
#pragma unroll
    for (int s = 0; s < 4; ++s)
#pragma unroll
      for (int e = 0; e < 4; ++e)
        if (k0 + s * 16 + lr > qs + lg * 4 + e) sc[s][e] = -INFINITY;
  }
  float scl[4];
#pragma unroll
  for (int e = 0; e < 4; ++e) {
    float mt = fmaxf(fmaxf(sc[0][e], sc[1][e]), fmaxf(sc[2][e], sc[3][e]));
#pragma unroll
    for (int o = 1; o < 16; o <<= 1) mt = fmaxf(mt, __shfl_xor(mt, o));
    const float mn = fmaxf(st.m[e], mt);
    const float sf = __expf(st.m[e] - mn);
    float p0 = __expf(sc[0][e] - mn), p1 = __expf(sc[1][e] - mn);
    float p2 = __expf(sc[2][e] - mn), p3 = __expf(sc[3][e] - mn);
    float rs = p0 + p1 + p2 + p3;
#pragma unroll
    for (int o = 1; o < 16; o <<= 1) rs += __shfl_xor(rs, o);
    st.l[e] = st.l[e] * sf + rs;
    st.m[e] = mn;
    scl[e] = sf;
    const int r = lg * 4 + e, sw = lg << 4;
    Pl[r][(0 * 16 + lr) ^ sw] = f2bf(p0);
    Pl[r][(1 * 16 + lr) ^ sw] = f2bf(p1);
    Pl[r][(2 * 16 + lr) ^ sw] = f2bf(p2);
    Pl[r][(3 * 16 + lr) ^ sw] = f2bf(p3);
  }
#pragma unroll
  for (int c = 0; c < 4; ++c) {
    st.acco[c][0] *= scl[0]; st.acco[c][1] *= scl[1];
    st.acco[c][2] *= scl[2]; st.acco[c][3] *= scl[3];
  }
  const int rsw = (lr >> 2) << 4;
  const s16x8 pa0 = *(const s16x8*)&Pl[lr][(lg * 8) ^ rsw];
  const s16x8 pa1 = *(const s16x8*)&Pl[lr][(32 + lg * 8) ^ rsw];
#pragma unroll
  for (int c = 0; c < 4; ++c) {
    st.acco[c] = MFMA16(pa0, vb[c][0], st.acco[c], 0, 0, 0);
    st.acco[c] = MFMA16(pa1, vb[c][1], st.acco[c], 0, 0, 0);
  }
}

DEV void attn_init(AttnChain& st, const u16* Qbase, int qs, int lr, int lg) {
  const u16* qp = Qbase + (size_t)(qs + lr) * 64 + lg * 8;
  st.aq0 = *(const s16x8*)qp;
  st.aq1 = *(const s16x8*)(qp + 32);
#pragma unroll
  for (int e = 0; e < 4; ++e) {
    st.m[e] = -INFINITY;
    st.l[e] = 0.f;
    st.acco[e] = f32x4{};
  }
}

DEV void attn_fin(const AttnChain& st, u16* __restrict__ ctx, int bh, int qs,
                  int lr, int lg) {
  const int bb = bh >> 4, hh = bh & 15;
#pragma unroll
  for (int c = 0; c < 4; ++c) {
    const int d = c * 16 + lr;
#pragma unroll
    for (int e = 0; e < 4; ++e) {
      const int q = qs + lg * 4 + e;
      ctx[(size_t)(bb * 2048 + q) * 1024 + hh * 64 + d] =
          f2bf(st.acco[c][e] / st.l[e]);
    }
  }
}

__global__ __launch_bounds__(64) void attn_kernel(
    const u16* __restrict__ Qg, const u16* __restrict__ Kg,
    const u16* __restrict__ Vt, u16* __restrict__ ctx) {
  __shared__ __align__(16) u16 Pl[2][16][64];
  const int lane = threadIdx.x & 63;
  const int wx = blockIdx.x, bh = blockIdx.y;
  const int lr = lane & 15, lg = lane >> 4;
  const int tA = wx, tB = 127 - wx;             // paired q-tiles
  const int qsA = tA * 16, qsB = tB * 16;
  const int ntA = tA / 4 + 1, ntB = tB / 4 + 1; // 64-key tiles per chain
  const size_t baseK = (size_t)bh * 2048 * 64;
  const size_t baseV = (size_t)bh * 64 * 2048;
  const u16* Kb = Kg + baseK;
  const u16* Vb = Vt + baseV;

  AttnChain A, B;
  attn_init(A, Qg + baseK, qsA, lr, lg);
  attn_init(B, Qg + baseK, qsB, lr, lg);

  // interleaved common part (branch-free bodies -> one schedulable block)
  for (int kt = 0; kt < ntA - 1; ++kt) {
    attn_tile<false>(B, kt * 64, qsB, Kb, Vb, Pl[1], lr, lg);
    attn_tile<false>(A, kt * 64, qsA, Kb, Vb, Pl[0], lr, lg);
  }
  {  // A's diagonal tile, B still inner
    const int kt = ntA - 1;
    attn_tile<false>(B, kt * 64, qsB, Kb, Vb, Pl[1], lr, lg);
    attn_tile<true>(A, kt * 64, qsA, Kb, Vb, Pl[0], lr, lg);
  }
  attn_fin(A, ctx, bh, qsA, lr, lg);
  for (int kt = ntA; kt < ntB - 1; ++kt)
    attn_tile<false>(B, kt * 64, qsB, Kb, Vb, Pl[1], lr, lg);
  attn_tile<true>(B, (ntB - 1) * 64, qsB, Kb, Vb, Pl[1], lr, lg);
  attn_fin(B, ctx, bh, qsB, lr, lg);
}

// ---------------------------------------------------------------------------
extern "C" void kernel_launch(void* const* d_in, const int* in_sizes, int n_in,
                              void* d_out, int out_size, void* d_ws,
                              size_t ws_size, hipStream_t stream) {
  const float* x  = (const float*)d_in[0];
  const float* wq = (const float*)d_in[1];
  const float* wk = (const float*)d_in[2];
  const float* wv = (const float*)d_in[3];
  const float* wo = (const float*)d_in[4];
  const float* bo = (const float*)d_in[5];
  const float* w1 = (const float*)d_in[6];
  const float* b1 = (const float*)d_in[7];
  const float* w2 = (const float*)d_in[8];
  const float* b2 = (const float*)d_in[9];
  const float* g1 = (const float*)d_in[10];
  const float* s1 = (const float*)d_in[11];
  const float* g2 = (const float*)d_in[12];
  const float* s2 = (const float*)d_in[13];
  float* out = (float*)d_out;

  const size_t MB = (size_t)1 << 20;
  char* p = (char*)d_ws;
  u16* hb    = (u16*)(p + 0 * MB);
  u16* qbuf  = (u16*)(p + 8 * MB);    // q | k [32][2048][64], vt [32][64][2048]
  u16* ctxb  = (u16*)(p + 32 * MB);
  float* x2  = (float*)(p + 40 * MB);
  u16* h2b   = (u16*)(p + 56 * MB);
  u16* qkvw  = (u16*)(p + 64 * MB);   // [3072][1024] packed Wq/Wk/Wv^T
  u16* wot   = (u16*)(p + 70 * MB);
  u16* w1t   = (u16*)(p + 72 * MB);
  u16* w2t   = (u16*)(p + 80 * MB);
  u16* gb    = (u16*)(p + 0 * MB);    // gelu out, aliases hb/qbuf

  const dim3 blk(256);
  tconv_kernel<<<dim3(16, 16), blk, 0, stream>>>(wq, qkvw, 1024, 1024);
  tconv_kernel<<<dim3(16, 16), blk, 0, stream>>>(wk, qkvw + 1048576, 1024, 1024);
  tconv_kernel<<<dim3(16, 16), blk, 0, stream>>>(wv, qkvw + 2097152, 1024, 1024);
  tconv_kernel<<<dim3(16, 16), blk, 0, stream>>>(wo, wot, 1024, 1024);
  tconv_kernel<<<dim3(64, 16), blk, 0, stream>>>(w1, w1t, 1024, 4096);
  tconv_kernel<<<dim3(16, 64), blk, 0, stream>>>(w2, w2t, 4096, 1024);

  ln_kernel<<<4096, blk, 0, stream>>>(x, g1, s1, hb);
  gemm_kernel<0><<<dim3(24, 32), blk, 0, stream>>>(hb, qkvw, nullptr, nullptr,
                                                   qbuf, 4096, 3072, 1024);
  attn_kernel<<<dim3(64, 32), dim3(64), 0, stream>>>(
      qbuf, qbuf + 4194304, qbuf + 8388608, ctxb);
  gemm_kernel<1><<<dim3(8, 32), blk, 0, stream>>>(ctxb, wot, bo, x, x2, 4096,
                                                  1024, 1024);
  ln_kernel<<<4096, blk, 0, stream>>>(x2, g2, s2, h2b);
  gemm_kernel<2><<<dim3(32, 32), blk, 0, stream>>>(h2b, w1t, b1, nullptr, gb,
                                                   4096, 4096, 1024);
  gemm_kernel<1><<<dim3(8, 32), blk, 0, stream>>>(gb, w2t, b2, x2, out, 4096,
                                                  1024, 4096);
}

// Round 4
// 381.822 us; speedup vs baseline: 2.3033x; 1.0154x over previous
//
#include <hip/hip_runtime.h>

// TransformerBlock: B=2, S=2048, D=1024, H=16, dh=64, FFN=4096.
// Round 4: swapped-operand QK^T/PV attention — softmax fully lane-local.

typedef __attribute__((ext_vector_type(8))) short s16x8;
typedef __attribute__((ext_vector_type(4))) float f32x4;
typedef unsigned short u16;
typedef unsigned int u32;

#define DEV static __device__ __forceinline__
#define MFMA16 __builtin_amdgcn_mfma_f32_16x16x32_bf16
#define GLOAD_LDS16(gp, lp)                                         \
  __builtin_amdgcn_global_load_lds(                                 \
      (const __attribute__((address_space(1))) void*)(gp),          \
      (__attribute__((address_space(3))) void*)(lp), 16, 0, 0)

DEV u16 f2bf(float f) {
  union { float f; unsigned u; } c; c.f = f;
  unsigned u = c.u;
  u += 0x7fff + ((u >> 16) & 1);   // RNE
  return (u16)(u >> 16);
}

DEV u32 cvtpk(float lo, float hi) {  // packed f32x2 -> bf16x2 (RNE)
  u32 r;
  asm("v_cvt_pk_bf16_f32 %0, %1, %2" : "=v"(r) : "v"(lo), "v"(hi));
  return r;
}

DEV float gelu_tanh(float v) {
  const float c0 = 0.7978845608028654f;  // sqrt(2/pi)
  float u = c0 * (v + 0.044715f * v * v * v);
  return 0.5f * v * (1.0f + tanhf(u));
}

// ---------- transpose + convert: W fp32 [K,N] -> Wt bf16 [N,K] -------------
__global__ __launch_bounds__(256) void tconv_kernel(
    const float* __restrict__ W, u16* __restrict__ Wt, int K, int N) {
  __shared__ u16 T[64][80];
  const int t = threadIdx.x;
  const int n0 = blockIdx.x * 64, k0 = blockIdx.y * 64;
  const int kr = t >> 4, nc = (t & 15) * 4;
#pragma unroll
  for (int p = 0; p < 4; ++p) {
    const int k = p * 16 + kr;
    float4 v = *(const float4*)(W + (size_t)(k0 + k) * N + n0 + nc);
    T[nc + 0][k] = f2bf(v.x);
    T[nc + 1][k] = f2bf(v.y);
    T[nc + 2][k] = f2bf(v.z);
    T[nc + 3][k] = f2bf(v.w);
  }
  __syncthreads();
  const int nr = t >> 2, kc = (t & 3) * 16;
  *(s16x8*)(Wt + (size_t)(n0 + nr) * K + k0 + kc) = *(const s16x8*)&T[nr][kc];
  *(s16x8*)(Wt + (size_t)(n0 + nr) * K + k0 + kc + 8) =
      *(const s16x8*)&T[nr][kc + 8];
}

// ---------------- LayerNorm: fp32 [rows,1024] -> bf16 [rows,1024] ----------
__global__ __launch_bounds__(256) void ln_kernel(
    const float* __restrict__ x, const float* __restrict__ g,
    const float* __restrict__ b, u16* __restrict__ out) {
  const int row = blockIdx.x;
  const int t = threadIdx.x;
  const float* xr = x + (size_t)row * 1024;
  float4 v = *(const float4*)(xr + t * 4);
  float s = v.x + v.y + v.z + v.w;
  float ss = v.x * v.x + v.y * v.y + v.z * v.z + v.w * v.w;
#pragma unroll
  for (int off = 1; off < 64; off <<= 1) {
    s += __shfl_xor(s, off);
    ss += __shfl_xor(ss, off);
  }
  __shared__ float sb[4], ssb[4];
  const int w = t >> 6;
  if ((t & 63) == 0) { sb[w] = s; ssb[w] = ss; }
  __syncthreads();
  s = sb[0] + sb[1] + sb[2] + sb[3];
  ss = ssb[0] + ssb[1] + ssb[2] + ssb[3];
  const float mean = s * (1.0f / 1024.0f);
  const float var = ss * (1.0f / 1024.0f) - mean * mean;
  const float rstd = rsqrtf(var + 1e-5f);
  const int c = t * 4;
  ushort4 o;
  o.x = f2bf(g[c + 0] * ((v.x - mean) * rstd) + b[c + 0]);
  o.y = f2bf(g[c + 1] * ((v.y - mean) * rstd) + b[c + 1]);
  o.z = f2bf(g[c + 2] * ((v.z - mean) * rstd) + b[c + 2]);
  o.w = f2bf(g[c + 3] * ((v.w - mean) * rstd) + b[c + 3]);
  *(ushort4*)(out + (size_t)row * 1024 + c) = o;
}

// ---------------- GEMM: C[M,N] = A(bf16)[M,K] @ Bt(bf16)[N,K]^T ------------
template <int EPI>
__global__ __launch_bounds__(256) void gemm_kernel(
    const u16* __restrict__ A, const u16* __restrict__ Bt,
    const float* __restrict__ bias, const float* __restrict__ res,
    void* __restrict__ Cv, int M, int N, int K) {
  __shared__ __align__(16) u16 Al[128][32];
  __shared__ __align__(16) u16 Bl[128][32];
  const int t = threadIdx.x;
  const int lane = t & 63, w = t >> 6;
  const int wm = (w >> 1) * 64, wn = (w & 1) * 64;
  const int bm = blockIdx.y * 128, bn = blockIdx.x * 128;
  const int lr = lane & 15, lg = lane >> 4;
  const int srow = lane >> 2, scol = (lane & 3) * 8;
  f32x4 acc[4][4] = {};

  for (int kt = 0; kt < K; kt += 32) {
    __syncthreads();
#pragma unroll
    for (int p = 0; p < 2; ++p) {
      const int r0 = (w * 2 + p) * 16;
      GLOAD_LDS16(A + (size_t)(bm + r0 + srow) * K + kt + scol, &Al[r0][0]);
      GLOAD_LDS16(Bt + (size_t)(bn + r0 + srow) * K + kt + scol, &Bl[r0][0]);
    }
    __syncthreads();
    s16x8 af[4], bf[4];
#pragma unroll
    for (int i = 0; i < 4; ++i) {
      af[i] = *(const s16x8*)&Al[wm + i * 16 + lr][lg * 8];
      bf[i] = *(const s16x8*)&Bl[wn + i * 16 + lr][lg * 8];
    }
#pragma unroll
    for (int i = 0; i < 4; ++i)
#pragma unroll
      for (int j = 0; j < 4; ++j)
        acc[i][j] = MFMA16(af[i], bf[j], acc[i][j], 0, 0, 0);
  }

#pragma unroll
  for (int i = 0; i < 4; ++i) {
    const int row = bm + wm + i * 16 + lg * 4;  // + e
#pragma unroll
    for (int j = 0; j < 4; ++j) {
      const int col = bn + wn + j * 16 + lr;
      if (EPI == 0) {
        const int bb = row >> 11, sloc = row & 2047;
        const int which = col >> 10, n = col & 1023;
        const int hh = n >> 6, dd = n & 63;
        u16* qbuf = (u16*)Cv;
        if (which == 2) {  // V transposed [bh][64][2048]
          ushort4 o;
          o.x = f2bf(acc[i][j][0]); o.y = f2bf(acc[i][j][1]);
          o.z = f2bf(acc[i][j][2]); o.w = f2bf(acc[i][j][3]);
          *(ushort4*)(qbuf + 8388608 +
                      (size_t)((bb * 16 + hh) * 64 + dd) * 2048 + sloc) = o;
        } else {
          // q pre-scaled by (1/8)*log2(e) so attention runs in exp2 space
          const float sc = (which == 0) ? 0.18033688011112042f : 1.0f;
          u16* dst = qbuf + (size_t)which * 4194304 +
                     ((size_t)(bb * 16 + hh) * 2048 + sloc) * 64 + dd;
#pragma unroll
          for (int e = 0; e < 4; ++e) dst[(size_t)e * 64] = f2bf(acc[i][j][e] * sc);
        }
      } else if (EPI == 1) {
        float* C = (float*)Cv;
        const float bs = bias[col];
#pragma unroll
        for (int e = 0; e < 4; ++e)
          C[(size_t)(row + e) * N + col] =
              acc[i][j][e] + bs + res[(size_t)(row + e) * N + col];
      } else {
        u16* C = (u16*)Cv;
        const float bs = bias[col];
#pragma unroll
        for (int e = 0; e < 4; ++e)
          C[(size_t)(row + e) * N + col] = f2bf(gelu_tanh(acc[i][j][e] + bs));
      }
    }
  }
}

// ---------------- Flash attention: swapped-operand, dual-chain -------------
// Qg,Kg: [32][2048][64] bf16 (q pre-scaled to exp2 space); Vt: [32][64][2048].
// Block = 1 wave; chain A = q-tile wx, chain B = q-tile 127-wx.
// All softmax state lives at q = lane&15 (4 lg-lanes redundant/partitioned).
struct AttnChain {
  s16x8 aq0, aq1;   // Q[q=lr][d=lg*8+j], halves d<32 / d>=32
  f32x4 acco[4];    // O[q=lr][d = c*16 + lg*4 + e]
  float m, l;       // running max / denom for row q=lr (log2 space)
};

template <bool DIAG>
DEV void attn_tile(AttnChain& st, int k0, int qs, const u16* Kbase,
                   const u16* Vbase, u32* Prow, int lr, int lg, int swz) {
  // K fragments: K[key=k0+s*16+lr][d]
  s16x8 kb0[4], kb1[4];
#pragma unroll
  for (int s = 0; s < 4; ++s) {
    const u16* kp = Kbase + (size_t)(k0 + s * 16 + lr) * 64 + lg * 8;
    kb0[s] = *(const s16x8*)kp;
    kb1[s] = *(const s16x8*)(kp + 32);
  }
  // S^T = K Q^T: lane holds S[key=k0+s*16+lg*4+e][q=qs+lr]
  f32x4 sc[4];
#pragma unroll
  for (int s = 0; s < 4; ++s) {
    f32x4 a = {};
    a = MFMA16(kb0[s], st.aq0, a, 0, 0, 0);
    a = MFMA16(kb1[s], st.aq1, a, 0, 0, 0);
    sc[s] = a;
  }
  // V fragments in flight during softmax: V^T[d=c*16+lr][key]
  s16x8 vb0[4], vb1[4];
#pragma unroll
  for (int c = 0; c < 4; ++c) {
    const u16* vp = Vbase + (size_t)(c * 16 + lr) * 2048 + k0 + lg * 8;
    vb0[c] = *(const s16x8*)vp;
    vb1[c] = *(const s16x8*)(vp + 32);
  }
  if (DIAG) {
#pragma unroll
    for (int s = 0; s < 4; ++s)
#pragma unroll
      for (int e = 0; e < 4; ++e)
        if (k0 + s * 16 + lg * 4 + e > qs + lr) sc[s][e] = -INFINITY;
  }
  // row max: in-lane 16 + 2 shfl (across lg partition)
  float mt = fmaxf(fmaxf(sc[0][0], sc[0][1]), fmaxf(sc[0][2], sc[0][3]));
#pragma unroll
  for (int s = 1; s < 4; ++s)
    mt = fmaxf(mt, fmaxf(fmaxf(sc[s][0], sc[s][1]), fmaxf(sc[s][2], sc[s][3])));
  mt = fmaxf(mt, __shfl_xor(mt, 16));
  mt = fmaxf(mt, __shfl_xor(mt, 32));
  const float mn = fmaxf(st.m, mt);
  const float sf = exp2f(st.m - mn);
  float p[4][4];
  float rs = 0.f;
#pragma unroll
  for (int s = 0; s < 4; ++s)
#pragma unroll
    for (int e = 0; e < 4; ++e) {
      p[s][e] = exp2f(sc[s][e] - mn);
      rs += p[s][e];
    }
  rs += __shfl_xor(rs, 16);
  rs += __shfl_xor(rs, 32);
  st.l = st.l * sf + rs;
  st.m = mn;
  // pack P -> LDS (swizzled), re-read as MFMA B-frag P[q=lr][k=lg*8+j]
#pragma unroll
  for (int s = 0; s < 4; ++s) {
    uint2 wv;
    wv.x = cvtpk(p[s][0], p[s][1]);
    wv.y = cvtpk(p[s][2], p[s][3]);
    *(uint2*)&Prow[(s * 8 + lg * 2) ^ swz] = wv;
  }
  const s16x8 pa0 = *(const s16x8*)&Prow[(lg * 4) ^ swz];
  const s16x8 pa1 = *(const s16x8*)&Prow[(16 + lg * 4) ^ swz];
  // rescale + O^T += V^T P^T  (stays in q=lr space)
#pragma unroll
  for (int c = 0; c < 4; ++c) {
    acco_scale:;
    f32x4 a = st.acco[c];
    a[0] *= sf; a[1] *= sf; a[2] *= sf; a[3] *= sf;
    st.acco[c] = a;
  }
#pragma unroll
  for (int c = 0; c < 4; ++c) {
    st.acco[c] = MFMA16(vb0[c], pa0, st.acco[c], 0, 0, 0);
    st.acco[c] = MFMA16(vb1[c], pa1, st.acco[c], 0, 0, 0);
  }
}

DEV void attn_init(AttnChain& st, const u16* Qbase, int qs, int lr, int lg) {
  const u16* qp = Qbase + (size_t)(qs + lr) * 64 + lg * 8;
  st.aq0 = *(const s16x8*)qp;
  st.aq1 = *(const s16x8*)(qp + 32);
  st.m = -INFINITY;
  st.l = 0.f;
#pragma unroll
  for (int c = 0; c < 4; ++c) st.acco[c] = f32x4{};
}

DEV void attn_fin(const AttnChain& st, u16* __restrict__ ctx, int bh, int qs,
                  int lr, int lg) {
  const int bb = bh >> 4, hh = bh & 15;
  const float inv = 1.0f / st.l;
  const size_t rowoff = (size_t)(bb * 2048 + qs + lr) * 1024 + hh * 64 + lg * 4;
#pragma unroll
  for (int c = 0; c < 4; ++c) {
    uint2 o;
    o.x = cvtpk(st.acco[c][0] * inv, st.acco[c][1] * inv);
    o.y = cvtpk(st.acco[c][2] * inv, st.acco[c][3] * inv);
    *(uint2*)(ctx + rowoff + c * 16) = o;
  }
}

__global__ __launch_bounds__(64, 2) void attn_kernel(
    const u16* __restrict__ Qg, const u16* __restrict__ Kg,
    const u16* __restrict__ Vt, u16* __restrict__ ctx) {
  __shared__ __align__(16) u32 P32[2][16][32];
  const int lane = threadIdx.x & 63;
  const int wx = blockIdx.x, bh = blockIdx.y;
  const int lr = lane & 15, lg = lane >> 4;
  const int swz = (lr & 7) << 2;
  const int tA = wx, tB = 127 - wx;
  const int qsA = tA * 16, qsB = tB * 16;
  const int ntA = tA / 4 + 1, ntB = tB / 4 + 1;
  const size_t baseK = (size_t)bh * 2048 * 64;
  const size_t baseV = (size_t)bh * 64 * 2048;
  const u16* Kb = Kg + baseK;
  const u16* Vb = Vt + baseV;
  u32* PrA = &P32[0][lane & 15][0];
  u32* PrB = &P32[1][lane & 15][0];

  AttnChain A, B;
  attn_init(A, Qg + baseK, qsA, lr, lg);
  attn_init(B, Qg + baseK, qsB, lr, lg);

  for (int kt = 0; kt < ntA - 1; ++kt) {
    attn_tile<false>(B, kt * 64, qsB, Kb, Vb, PrB, lr, lg, swz);
    attn_tile<false>(A, kt * 64, qsA, Kb, Vb, PrA, lr, lg, swz);
  }
  {
    const int kt = ntA - 1;
    attn_tile<false>(B, kt * 64, qsB, Kb, Vb, PrB, lr, lg, swz);
    attn_tile<true>(A, kt * 64, qsA, Kb, Vb, PrA, lr, lg, swz);
  }
  attn_fin(A, ctx, bh, qsA, lr, lg);
  for (int kt = ntA; kt < ntB - 1; ++kt)
    attn_tile<false>(B, kt * 64, qsB, Kb, Vb, PrB, lr, lg, swz);
  attn_tile<true>(B, (ntB - 1) * 64, qsB, Kb, Vb, PrB, lr, lg, swz);
  attn_fin(B, ctx, bh, qsB, lr, lg);
}

// ---------------------------------------------------------------------------
extern "C" void kernel_launch(void* const* d_in, const int* in_sizes, int n_in,
                              void* d_out, int out_size, void* d_ws,
                              size_t ws_size, hipStream_t stream) {
  const float* x  = (const float*)d_in[0];
  const float* wq = (const float*)d_in[1];
  const float* wk = (const float*)d_in[2];
  const float* wv = (const float*)d_in[3];
  const float* wo = (const float*)d_in[4];
  const float* bo = (const float*)d_in[5];
  const float* w1 = (const float*)d_in[6];
  const float* b1 = (const float*)d_in[7];
  const float* w2 = (const float*)d_in[8];
  const float* b2 = (const float*)d_in[9];
  const float* g1 = (const float*)d_in[10];
  const float* s1 = (const float*)d_in[11];
  const float* g2 = (const float*)d_in[12];
  const float* s2 = (const float*)d_in[13];
  float* out = (float*)d_out;

  const size_t MB = (size_t)1 << 20;
  char* p = (char*)d_ws;
  u16* hb    = (u16*)(p + 0 * MB);
  u16* qbuf  = (u16*)(p + 8 * MB);    // q | k [32][2048][64], vt [32][64][2048]
  u16* ctxb  = (u16*)(p + 32 * MB);
  float* x2  = (float*)(p + 40 * MB);
  u16* h2b   = (u16*)(p + 56 * MB);
  u16* qkvw  = (u16*)(p + 64 * MB);   // [3072][1024] packed Wq/Wk/Wv^T
  u16* wot   = (u16*)(p + 70 * MB);
  u16* w1t   = (u16*)(p + 72 * MB);
  u16* w2t   = (u16*)(p + 80 * MB);
  u16* gb    = (u16*)(p + 0 * MB);    // gelu out, aliases hb/qbuf

  const dim3 blk(256);
  tconv_kernel<<<dim3(16, 16), blk, 0, stream>>>(wq, qkvw, 1024, 1024);
  tconv_kernel<<<dim3(16, 16), blk, 0, stream>>>(wk, qkvw + 1048576, 1024, 1024);
  tconv_kernel<<<dim3(16, 16), blk, 0, stream>>>(wv, qkvw + 2097152, 1024, 1024);
  tconv_kernel<<<dim3(16, 16), blk, 0, stream>>>(wo, wot, 1024, 1024);
  tconv_kernel<<<dim3(64, 16), blk, 0, stream>>>(w1, w1t, 1024, 4096);
  tconv_kernel<<<dim3(16, 64), blk, 0, stream>>>(w2, w2t, 4096, 1024);

  ln_kernel<<<4096, blk, 0, stream>>>(x, g1, s1, hb);
  gemm_kernel<0><<<dim3(24, 32), blk, 0, stream>>>(hb, qkvw, nullptr, nullptr,
                                                   qbuf, 4096, 3072, 1024);
  attn_kernel<<<dim3(64, 32), dim3(64), 0, stream>>>(
      qbuf, qbuf + 4194304, qbuf + 8388608, ctxb);
  gemm_kernel<1><<<dim3(8, 32), blk, 0, stream>>>(ctxb, wot, bo, x, x2, 4096,
                                                  1024, 1024);
  ln_kernel<<<4096, blk, 0, stream>>>(x2, g2, s2, h2b);
  gemm_kernel<2><<<dim3(32, 32), blk, 0, stream>>>(h2b, w1t, b1, nullptr, gb,
                                                   4096, 4096, 1024);
  gemm_kernel<1><<<dim3(8, 32), blk, 0, stream>>>(gb, w2t, b2, x2, out, 4096,
                                                  1024, 4096);
}